// Round 5
// baseline (217.068 us; speedup 1.0000x reference)
//
#include <hip/hip_runtime.h>

// LSTM_WP: B=4096 batch-1 LSTMs, T=H=128, input_size=1, fused MFMA-f16 recurrence.
// Round 5: phase-drift. r4 falsified the weight-reload theory (in-loop pin was a
// total no-op -> weights already AGPR-resident). Real limiter: ~900 cyc/step of
// barrier/latency bubbles, unhidden at 1 block/CU with all waves phase-locked.
// Fix: 512 blocks x 8 batches, 2 co-resident blocks/CU with independent barrier
// phases -> one block's MFMA fills the other's ew/barrier bubbles.
// MFMA M=16 rows duplicated (row m = batch m&7; C rows m, m+8 identical), and the
// elementwise update is split so each lane handles 2 rows covering every
// (batch,column) exactly once: q<2 -> rows{0,1}, q>=2 -> rows{2,3}, b=(q*4+r)&7.
// ew/trans work per CU is conserved; MFMA doubles (it had headroom).

#define H   128
#define T   128
#define MB  8           // batches per block
#define BLOCK 512
#define HSTRIDE 136     // f16 per h row: 272 B -> b128-aligned, 2-way banks (free)
#define XSTRIDE 12      // f32 per xs row: 48 B, 16B-aligned

typedef _Float16 f16x8 __attribute__((ext_vector_type(8)));
typedef float    f32x4 __attribute__((ext_vector_type(4)));

// ---------------- prep: W_hh f32 [512][128] -> f16 fragment-contiguous ----------------
// layout: idx(ct,g,kc,q,l15) = (((ct*4+g)*4+kc)*4+q)*16+l15, 8 f16 each (16 B).
__global__ void prep_whh_kernel(const float* __restrict__ W_hh, _Float16* __restrict__ wfrag)
{
    int idx = blockIdx.x * blockDim.x + threadIdx.x;     // 0..8191
    int l15 =  idx        & 15;
    int q   = (idx >> 4)  & 3;
    int kc  = (idx >> 6)  & 3;
    int g   = (idx >> 8)  & 3;
    int ct  = (idx >> 10) & 7;
    int n  = g * H + ct * 16 + l15;                      // gate row in [0,512)
    int k0 = kc * 32 + q * 8;
    const float* src = W_hh + (size_t)n * H + k0;
    f16x8 f;
    #pragma unroll
    for (int i = 0; i < 8; ++i) f[i] = (_Float16)src[i];
    *(f16x8*)(wfrag + (size_t)idx * 8) = f;
}

__device__ __forceinline__ float frcp(float v) { return __builtin_amdgcn_rcpf(v); }

__launch_bounds__(BLOCK, 4)
__global__ void lstm_fused_kernel(const float* __restrict__ x,
                                  const float* __restrict__ W_ih,
                                  const _Float16* __restrict__ wfrag,
                                  const float* __restrict__ b_ih,
                                  const float* __restrict__ b_hh,
                                  const float* __restrict__ fc_W,
                                  const float* __restrict__ fc_b,
                                  float* __restrict__ out)
{
    __shared__ __align__(16) float xs[T + 1][XSTRIDE];           // 6.2 KB (+1 row: prefetch pad)
    __shared__ __align__(16) _Float16 hbuf[2][MB][HSTRIDE];      // 4.25 KB h double-buffer

    const int tid  = threadIdx.x;
    const int wave = tid >> 6;          // column tile 0..7
    const int lane = tid & 63;
    const int l15  = lane & 15;
    const int q    = lane >> 4;         // 0..3
    const int jcol = wave * 16 + l15;   // hidden column 0..127

    // ew row assignment: q<2 -> rows {0,1}, q>=2 -> rows {2,3}; batch=(q*4+r)&7
    const int r0 = (q >> 1) * 2;        // 0 or 2
    const int b0 = (q * 4 + r0) & 7;    // batch for row r0 (r0+1 -> b0+1)

    // ---- stage x: [b][t] global -> xs[t][b] (8 batches x 128 t, one-time) ----
    {
        const int t0 = tid & 127;
        const int bb = tid >> 7;        // 0..3
        const float* xb = x + (size_t)blockIdx.x * (MB * T);
        xs[t0][bb]     = xb[bb * T + t0];
        xs[t0][bb + 4] = xb[(bb + 4) * T + t0];
    }
    for (int i = tid; i < MB * HSTRIDE; i += BLOCK)              // h0 = 0
        (&hbuf[0][0][0])[i] = (_Float16)0.0f;

    // ---- load pre-converted W_hh fragments (f16, lane-coalesced 16 B each) ----
    f16x8 wf[4][4];                     // [gate][kc]
    {
        const _Float16* wbase = wfrag + (size_t)wave * (4 * 4 * 4 * 16 * 8);
        #pragma unroll
        for (int g = 0; g < 4; ++g)
            #pragma unroll
            for (int kc = 0; kc < 4; ++kc)
                wf[g][kc] = *(const f16x8*)(wbase + ((((g * 4 + kc) * 4 + q) * 16 + l15) * 8));
    }

    float wih[4], bias[4];
    #pragma unroll
    for (int g = 0; g < 4; ++g) {
        const int n = g * H + jcol;
        wih[g]  = W_ih[n];
        bias[g] = b_ih[n] + b_hh[n];
    }

    float c0 = 0.f, c1 = 0.f;           // cell state for this lane's 2 assigned rows

    __syncthreads();

    // preact init for t=0: C row m corresponds to batch m&7
    f32x4 initv[4];
    {
        #pragma unroll
        for (int g = 0; g < 4; ++g)
            #pragma unroll
            for (int r = 0; r < 4; ++r)
                initv[g][r] = fmaf(xs[0][(q * 4 + r) & 7], wih[g], bias[g]);
    }

    for (int t = 0; t < T; ++t) {
        const int rb = t & 1;
        const int wb = rb ^ 1;

        // A-fragments: row m = batch m&7 (duplicated halves), k = kc*32 + q*8 + i
        f16x8 af[4];
        #pragma unroll
        for (int kc = 0; kc < 4; ++kc)
            af[kc] = *(const f16x8*)&hbuf[rb][l15 & 7][kc * 32 + q * 8];

        // gates = init + h @ W_hh^T; kc-outer g-inner -> 4 independent acc chains
        f32x4 acc[4];
        #pragma unroll
        for (int g = 0; g < 4; ++g)
            acc[g] = __builtin_amdgcn_mfma_f32_16x16x32_f16(af[0], wf[g][0], initv[g], 0, 0, 0);
        #pragma unroll
        for (int kc = 1; kc < 4; ++kc)
            #pragma unroll
            for (int g = 0; g < 4; ++g)
                acc[g] = __builtin_amdgcn_mfma_f32_16x16x32_f16(af[kc], wf[g][kc], acc[g], 0, 0, 0);

        // next step's init: independent of MFMA results -> issues in the MFMA shadow
        #pragma unroll
        for (int g = 0; g < 4; ++g)
            #pragma unroll
            for (int r = 0; r < 4; ++r)
                initv[g][r] = fmaf(xs[t + 1][(q * 4 + r) & 7], wih[g], bias[g]);

        // fused-rcp elementwise on this lane's 2 assigned rows (coverage exact)
        {
            const int r = r0;
            float ai = acc[0][r], afv = acc[1][r], ag = acc[2][r], ao = acc[3][r];
            float Ei = __expf(-ai);
            float Ef = __expf(-afv);
            float Eg = __expf(2.0f * ag);
            float u  = 1.0f + Ei;
            float v  = 1.0f + Ef;
            float w  = 1.0f + Eg;
            float wm = Eg - 1.0f;
            float uw = u * w;
            float cn = fmaf(c0, uw, wm * v) * frcp(v * uw);
            c0 = cn;
            float Eo = __expf(-ao);
            float Ec = __expf(2.0f * cn);
            float hv = (Ec - 1.0f) * frcp((Ec + 1.0f) * (1.0f + Eo));
            hbuf[wb][b0][jcol] = (_Float16)hv;
        }
        {
            const int r = r0 + 1;
            float ai = acc[0][r], afv = acc[1][r], ag = acc[2][r], ao = acc[3][r];
            float Ei = __expf(-ai);
            float Ef = __expf(-afv);
            float Eg = __expf(2.0f * ag);
            float u  = 1.0f + Ei;
            float v  = 1.0f + Ef;
            float w  = 1.0f + Eg;
            float wm = Eg - 1.0f;
            float uw = u * w;
            float cn = fmaf(c1, uw, wm * v) * frcp(v * uw);
            c1 = cn;
            float Eo = __expf(-ao);
            float Ec = __expf(2.0f * cn);
            float hv = (Ec - 1.0f) * frcp((Ec + 1.0f) * (1.0f + Eo));
            hbuf[wb][b0 + 1][jcol] = (_Float16)hv;
        }
        __syncthreads();
    }

    // ---- epilogue: out[b] = fc_b + sum_j fc_W[j] * hT[b][j]  (hT in hbuf[0]) ----
    if (tid < 128) {
        const int b    = tid >> 4;      // 0..7
        const int part = tid & 15;
        const _Float16* hrow = &hbuf[0][b][0];
        float s = 0.0f;
        #pragma unroll
        for (int i = 0; i < 8; ++i) {
            const int j = part * 8 + i;
            s += fc_W[j] * (float)hrow[j];
        }
        s += __shfl_xor(s, 8, 16);
        s += __shfl_xor(s, 4, 16);
        s += __shfl_xor(s, 2, 16);
        s += __shfl_xor(s, 1, 16);
        if (part == 0)
            out[blockIdx.x * MB + b] = s + fc_b[0];
    }
}

extern "C" void kernel_launch(void* const* d_in, const int* in_sizes, int n_in,
                              void* d_out, int out_size, void* d_ws, size_t ws_size,
                              hipStream_t stream)
{
    const float* x    = (const float*)d_in[0];
    const float* W_ih = (const float*)d_in[1];
    const float* W_hh = (const float*)d_in[2];
    const float* b_ih = (const float*)d_in[3];
    const float* b_hh = (const float*)d_in[4];
    const float* fc_W = (const float*)d_in[5];
    const float* fc_b = (const float*)d_in[6];
    float* out = (float*)d_out;

    _Float16* wfrag = (_Float16*)d_ws;     // 64K f16 = 128 KB fragment-ordered W_hh

    hipLaunchKernelGGL(prep_whh_kernel, dim3(32), dim3(256), 0, stream, W_hh, wfrag);

    const int B = in_sizes[0] / H;         // 4096 chunks
    dim3 grid(B / MB);                     // 512 blocks -> 2 per CU (phase drift)
    dim3 block(BLOCK);                     // 8 waves/block, 16 waves/CU
    hipLaunchKernelGGL(lstm_fused_kernel, grid, block, 0, stream,
                       x, W_ih, wfrag, b_ih, b_hh, fc_W, fc_b, out);
}